// Round 1
// baseline (243.919 us; speedup 1.0000x reference)
//
#include <hip/hip_runtime.h>

// PointPillarScatter on MI355X.
// out[b, c, g] = pf[b, c, p] where coords maps pillar (b,p) -> spatial g (if g>0), else 0.
// Strategy: invert scatter -> gather.
//   1) memset inv[] (in d_ws) to -1
//   2) build_inv: inv[b*G + s] = global pillar row i   (48k threads)
//   3) bev_gather: stream the whole 219MB output with coalesced float4 stores,
//      predicated gathers from the 12MB feature tensor where inv >= 0.

namespace {
constexpr int kB = 4;
constexpr int kP = 12000;
constexpr int kC = 64;
constexpr int kG = 432 * 496;        // 214272 spatial cells (NZ=1)
constexpr int kGq = kG / 4;          // 53568 float4 groups; divisible by 64 -> wave-uniform b,cc
constexpr int kCSplit = 8;           // channel chunks per (b,g4)
constexpr int kCPer = kC / kCSplit;  // 8 channels per thread
}  // namespace

__global__ __launch_bounds__(256) void build_inv_kernel(const int* __restrict__ coords,
                                                        int* __restrict__ inv) {
    int i = blockIdx.x * blockDim.x + threadIdx.x;
    if (i >= kB * kP) return;
    int b = coords[2 * i];      // batch index (dest), per reference semantics
    int s = coords[2 * i + 1];  // spatial index
    // reference: mask = spatial_idx > 0 ; per-batch perm -> no duplicates, no race
    if (s > 0 && s < kG && b >= 0 && b < kB) inv[b * kG + s] = i;
}

__global__ __launch_bounds__(256) void bev_gather_kernel(const float* __restrict__ pf,
                                                         const int* __restrict__ inv,
                                                         float* __restrict__ out) {
    int t = blockIdx.x * blockDim.x + threadIdx.x;
    int gq = t % kGq;          // fast dim -> coalesced stores/loads
    int bc = t / kGq;          // b * kCSplit + cc   (wave-uniform)
    int cc = bc & (kCSplit - 1);
    int b = bc >> 3;           // log2(kCSplit) == 3
    if (b >= kB) return;

    // 4 inverse-index entries for this thread's 4 consecutive g positions (16B coalesced)
    const int4 iv = *reinterpret_cast<const int4*>(inv + b * kG + 4 * gq);

    float a0[kCPer], a1[kCPer], a2[kCPer], a3[kCPer];
#pragma unroll
    for (int j = 0; j < kCPer; ++j) {
        a0[j] = 0.f; a1[j] = 0.f; a2[j] = 0.f; a3[j] = 0.f;
    }

    const int c0 = cc * kCPer;

    // Predicated gathers: ~5.6% of lanes active per region; exec mask skips the rest.
    // Source row i decomposes as (i/P, i%P); source addr = b_src*C*P + c*P + p_src.
    if (iv.x >= 0) {
        const float* src = pf + (iv.x / kP) * (kC * kP) + (iv.x % kP) + c0 * kP;
#pragma unroll
        for (int j = 0; j < kCPer; ++j) a0[j] = src[j * kP];
    }
    if (iv.y >= 0) {
        const float* src = pf + (iv.y / kP) * (kC * kP) + (iv.y % kP) + c0 * kP;
#pragma unroll
        for (int j = 0; j < kCPer; ++j) a1[j] = src[j * kP];
    }
    if (iv.z >= 0) {
        const float* src = pf + (iv.z / kP) * (kC * kP) + (iv.z % kP) + c0 * kP;
#pragma unroll
        for (int j = 0; j < kCPer; ++j) a2[j] = src[j * kP];
    }
    if (iv.w >= 0) {
        const float* src = pf + (iv.w / kP) * (kC * kP) + (iv.w % kP) + c0 * kP;
#pragma unroll
        for (int j = 0; j < kCPer; ++j) a3[j] = src[j * kP];
    }

    // 8 coalesced float4 stores (1KB per wave per store), one per channel in this chunk.
    float* ob = out + (size_t)b * kC * kG + (size_t)c0 * kG + 4 * gq;
#pragma unroll
    for (int j = 0; j < kCPer; ++j) {
        float4 v = make_float4(a0[j], a1[j], a2[j], a3[j]);
        *reinterpret_cast<float4*>(ob + (size_t)j * kG) = v;
    }
}

extern "C" void kernel_launch(void* const* d_in, const int* in_sizes, int n_in,
                              void* d_out, int out_size, void* d_ws, size_t ws_size,
                              hipStream_t stream) {
    const float* pf = (const float*)d_in[0];   // (B, C, P, 1) float32
    const int* coords = (const int*)d_in[1];   // (B*P, 2) int32 (harness converts ints)
    float* out = (float*)d_out;                // (B, C, NY, NX) float32 = B*C*G elems
    int* inv = (int*)d_ws;                     // B*G int32 = 3.43 MB scratch

    // inv = -1 everywhere (0xFF bytes). hipMemsetAsync is graph-capture safe.
    hipMemsetAsync(inv, 0xFF, (size_t)kB * kG * sizeof(int), stream);

    build_inv_kernel<<<(kB * kP + 255) / 256, 256, 0, stream>>>(coords, inv);

    const int total = kB * kCSplit * kGq;      // 1,714,176 threads
    bev_gather_kernel<<<total / 256, 256, 0, stream>>>(pf, inv, out);
}

// Round 5
// 236.601 us; speedup vs baseline: 1.0309x; 1.0309x over previous
//
#include <hip/hip_runtime.h>

// PointPillarScatter on MI355X — gather formulation with transposed feature staging.
//   out[b, c, g] = pf[b, c, p] where coords maps pillar row i=(b,p) -> spatial g (g>0), else 0.
// Pipeline:
//   1) memset inv[] (d_ws) to -1                       (3.4 MB)
//   2) build_inv: inv[b*G + s] = global pillar row i   (48k threads)
//   3) transpose: feats_t[i][c] = pf[b_i, c, p_i]      (12.3 MB, LDS transpose, coalesced)
//   4) bev_gather: stream 219 MB output with coalesced nontemporal float4 stores;
//      valid slots read 8 contiguous channels (2x float4) from feats_t.

namespace {
constexpr int kB = 4;
constexpr int kP = 12000;
constexpr int kC = 64;
constexpr int kG = 432 * 496;        // 214272 spatial cells (NZ=1)
constexpr int kGq = kG / 4;          // 53568; divisible by 64 -> wave-uniform b,cc
constexpr int kCSplit = 8;           // channel chunks per (b,g4)
constexpr int kCPer = kC / kCSplit;  // 8 channels per thread
constexpr int kTP = 64;              // p-tile for transpose
typedef float floatx4 __attribute__((ext_vector_type(4)));  // native vec for nontemporal store
}  // namespace

__global__ __launch_bounds__(256) void build_inv_kernel(const int* __restrict__ coords,
                                                        int* __restrict__ inv) {
    int i = blockIdx.x * blockDim.x + threadIdx.x;
    if (i >= kB * kP) return;
    int b = coords[2 * i];      // dest batch index
    int s = coords[2 * i + 1];  // spatial index; reference mask: s > 0
    if (s > 0 && s < kG && b >= 0 && b < kB) inv[b * kG + s] = i;
}

// feats_t[b*P + p][c] = pf[b][c][p]; coalesced global reads and writes via LDS tile.
__global__ __launch_bounds__(256) void transpose_kernel(const float* __restrict__ pf,
                                                        float* __restrict__ ft) {
    __shared__ float tile[kC][kTP + 1];  // [c][p], +1 pad
    const int b = blockIdx.y;
    const int p0 = blockIdx.x * kTP;
    const int tx = threadIdx.x % kTP;  // p within tile (wave-contiguous)
    const int tg = threadIdx.x / kTP;  // 0..3
    const int p = p0 + tx;

    if (p < kP) {
#pragma unroll
        for (int it = 0; it < 16; ++it) {
            int c = it * 4 + tg;
            tile[c][tx] = pf[((size_t)b * kC + c) * kP + p];
        }
    }
    __syncthreads();

    const int q = threadIdx.x % 16;  // channel quad (float4)
    const int r = threadIdx.x / 16;  // row-in-tile low bits
#pragma unroll
    for (int rr = 0; rr < 4; ++rr) {
        int pp = rr * 16 + r;
        int prow = p0 + pp;
        if (prow < kP) {
            floatx4 v = {tile[4 * q + 0][pp], tile[4 * q + 1][pp],
                         tile[4 * q + 2][pp], tile[4 * q + 3][pp]};
            *reinterpret_cast<floatx4*>(ft + ((size_t)b * kP + prow) * kC + 4 * q) = v;
        }
    }
}

__global__ __launch_bounds__(256) void bev_gather_kernel(const float* __restrict__ ft,
                                                         const int* __restrict__ inv,
                                                         float* __restrict__ out) {
    int t = blockIdx.x * blockDim.x + threadIdx.x;
    int gq = t % kGq;          // fast dim -> coalesced stores/loads
    int bc = t / kGq;          // b * kCSplit + cc   (wave-uniform)
    int cc = bc & (kCSplit - 1);
    int b = bc >> 3;
    if (b >= kB) return;

    const int4 iv = *reinterpret_cast<const int4*>(inv + b * kG + 4 * gq);
    const int c0 = cc * kCPer;

    float a0[kCPer], a1[kCPer], a2[kCPer], a3[kCPer];
#pragma unroll
    for (int j = 0; j < kCPer; ++j) { a0[j] = 0.f; a1[j] = 0.f; a2[j] = 0.f; a3[j] = 0.f; }

    // Valid slots (~5.6% lane density): 8 contiguous channels = 2x float4 each.
    if (iv.x >= 0) {
        const floatx4* s = reinterpret_cast<const floatx4*>(ft + (size_t)iv.x * kC + c0);
        *reinterpret_cast<floatx4*>(&a0[0]) = s[0];
        *reinterpret_cast<floatx4*>(&a0[4]) = s[1];
    }
    if (iv.y >= 0) {
        const floatx4* s = reinterpret_cast<const floatx4*>(ft + (size_t)iv.y * kC + c0);
        *reinterpret_cast<floatx4*>(&a1[0]) = s[0];
        *reinterpret_cast<floatx4*>(&a1[4]) = s[1];
    }
    if (iv.z >= 0) {
        const floatx4* s = reinterpret_cast<const floatx4*>(ft + (size_t)iv.z * kC + c0);
        *reinterpret_cast<floatx4*>(&a2[0]) = s[0];
        *reinterpret_cast<floatx4*>(&a2[4]) = s[1];
    }
    if (iv.w >= 0) {
        const floatx4* s = reinterpret_cast<const floatx4*>(ft + (size_t)iv.w * kC + c0);
        *reinterpret_cast<floatx4*>(&a3[0]) = s[0];
        *reinterpret_cast<floatx4*>(&a3[4]) = s[1];
    }

    // 8 coalesced nontemporal float4 stores (1KB/wave each); output is write-once.
    float* ob = out + (size_t)b * kC * kG + (size_t)c0 * kG + 4 * gq;
#pragma unroll
    for (int j = 0; j < kCPer; ++j) {
        floatx4 v = {a0[j], a1[j], a2[j], a3[j]};
        __builtin_nontemporal_store(v, reinterpret_cast<floatx4*>(ob + (size_t)j * kG));
    }
}

extern "C" void kernel_launch(void* const* d_in, const int* in_sizes, int n_in,
                              void* d_out, int out_size, void* d_ws, size_t ws_size,
                              hipStream_t stream) {
    const float* pf = (const float*)d_in[0];   // (B, C, P, 1) float32
    const int* coords = (const int*)d_in[1];   // (B*P, 2) int
    float* out = (float*)d_out;                // (B, C, NY, NX) float32
    int* inv = (int*)d_ws;                     // B*G int32 = 3.43 MB
    float* ft = (float*)((char*)d_ws + (size_t)kB * kG * sizeof(int));  // 48000x64 f32 = 12.3 MB

    (void)hipMemsetAsync(inv, 0xFF, (size_t)kB * kG * sizeof(int), stream);

    build_inv_kernel<<<(kB * kP + 255) / 256, 256, 0, stream>>>(coords, inv);

    dim3 tgrid((kP + kTP - 1) / kTP, kB);
    transpose_kernel<<<tgrid, 256, 0, stream>>>(pf, ft);

    const int total = kB * kCSplit * kGq;      // 1,714,176 threads
    bev_gather_kernel<<<total / 256, 256, 0, stream>>>(ft, inv, out);
}